// Round 6
// baseline (679.762 us; speedup 1.0000x reference)
//
#include <hip/hip_runtime.h>
#include <cmath>

constexpr unsigned HASH_SIZE = 1u << 19;
constexpr unsigned HASH_MASK = HASH_SIZE - 1u;
constexpr unsigned P2 = 2654435761u;
constexpr unsigned P3 = 805459861u;
constexpr int NKEYS = 65536;
constexpr int NSHARD = 8;

struct ResArr { float r[16]; };
typedef float f4 __attribute__((ext_vector_type(4)));

// ---------------- stage 1: per-block min/max partials (no atomics) ----------
__global__ __launch_bounds__(256) void he_minmax1(const float* __restrict__ x, int n,
                                                  float* __restrict__ part) {
    int tid = blockIdx.x * blockDim.x + threadIdx.x;
    int stride = gridDim.x * blockDim.x;
    float mn0 = INFINITY, mn1 = INFINITY, mn2 = INFINITY;
    float mx0 = -INFINITY, mx1 = -INFINITY, mx2 = -INFINITY;
    for (int i = tid; i < n; i += stride) {
        float a = x[3 * i + 0];
        float b = x[3 * i + 1];
        float c = x[3 * i + 2];
        mn0 = fminf(mn0, a); mx0 = fmaxf(mx0, a);
        mn1 = fminf(mn1, b); mx1 = fmaxf(mx1, b);
        mn2 = fminf(mn2, c); mx2 = fmaxf(mx2, c);
    }
    #pragma unroll
    for (int off = 32; off > 0; off >>= 1) {
        mn0 = fminf(mn0, __shfl_down(mn0, off));
        mn1 = fminf(mn1, __shfl_down(mn1, off));
        mn2 = fminf(mn2, __shfl_down(mn2, off));
        mx0 = fmaxf(mx0, __shfl_down(mx0, off));
        mx1 = fmaxf(mx1, __shfl_down(mx1, off));
        mx2 = fmaxf(mx2, __shfl_down(mx2, off));
    }
    __shared__ float s[6][4];
    int w = threadIdx.x >> 6;
    if ((threadIdx.x & 63) == 0) {
        s[0][w] = mn0; s[1][w] = mn1; s[2][w] = mn2;
        s[3][w] = mx0; s[4][w] = mx1; s[5][w] = mx2;
    }
    __syncthreads();
    if (threadIdx.x == 0) {
        float* p = part + 6 * blockIdx.x;
        p[0] = fminf(fminf(s[0][0], s[0][1]), fminf(s[0][2], s[0][3]));
        p[1] = fminf(fminf(s[1][0], s[1][1]), fminf(s[1][2], s[1][3]));
        p[2] = fminf(fminf(s[2][0], s[2][1]), fminf(s[2][2], s[2][3]));
        p[3] = fmaxf(fmaxf(s[3][0], s[3][1]), fmaxf(s[3][2], s[3][3]));
        p[4] = fmaxf(fmaxf(s[4][0], s[4][1]), fmaxf(s[4][2], s[4][3]));
        p[5] = fmaxf(fmaxf(s[5][0], s[5][1]), fmaxf(s[5][2], s[5][3]));
    }
}

// ---------------- stage 2: combine 256 partials ----------------------------
__global__ __launch_bounds__(256) void he_minmax2(const float* __restrict__ part,
                                                  float* __restrict__ mm) {
    int t = threadIdx.x;
    const float* p = part + 6 * t;
    float mn0 = p[0], mn1 = p[1], mn2 = p[2];
    float mx0 = p[3], mx1 = p[4], mx2 = p[5];
    #pragma unroll
    for (int off = 32; off > 0; off >>= 1) {
        mn0 = fminf(mn0, __shfl_down(mn0, off));
        mn1 = fminf(mn1, __shfl_down(mn1, off));
        mn2 = fminf(mn2, __shfl_down(mn2, off));
        mx0 = fmaxf(mx0, __shfl_down(mx0, off));
        mx1 = fmaxf(mx1, __shfl_down(mx1, off));
        mx2 = fmaxf(mx2, __shfl_down(mx2, off));
    }
    __shared__ float s[6][4];
    int w = t >> 6;
    if ((t & 63) == 0) {
        s[0][w] = mn0; s[1][w] = mn1; s[2][w] = mn2;
        s[3][w] = mx0; s[4][w] = mx1; s[5][w] = mx2;
    }
    __syncthreads();
    if (t == 0) {
        mm[0] = fminf(fminf(s[0][0], s[0][1]), fminf(s[0][2], s[0][3]));
        mm[1] = fminf(fminf(s[1][0], s[1][1]), fminf(s[1][2], s[1][3]));
        mm[2] = fminf(fminf(s[2][0], s[2][1]), fminf(s[2][2], s[2][3]));
        mm[3] = fmaxf(fmaxf(s[3][0], s[3][1]), fmaxf(s[3][2], s[3][3]));
        mm[4] = fmaxf(fmaxf(s[4][0], s[4][1]), fmaxf(s[4][2], s[4][3]));
        mm[5] = fmaxf(fmaxf(s[5][0], s[5][1]), fmaxf(s[5][2], s[5][3]));
    }
}

// ---------------- sort passes ------------------------------------------------
__device__ __forceinline__ unsigned spread5(unsigned v) {
    return (v & 1u) | ((v & 2u) << 2) | ((v & 4u) << 4) | ((v & 8u) << 6) | ((v & 16u) << 8);
}

__global__ __launch_bounds__(256) void he_keys(const float* __restrict__ x, int n,
                                               const float* __restrict__ mm,
                                               unsigned* __restrict__ planes,
                                               unsigned short* __restrict__ keyA) {
    int i = blockIdx.x * 256 + threadIdx.x;
    if (i >= n) return;
    float den0 = (mm[3] - mm[0]) + 1e-8f;
    float den1 = (mm[4] - mm[1]) + 1e-8f;
    float den2 = (mm[5] - mm[2]) + 1e-8f;
    float xs = (x[3 * i + 0] - mm[0]) / den0;
    float ys = (x[3 * i + 1] - mm[1]) / den1;
    float zs = (x[3 * i + 2] - mm[2]) / den2;
    unsigned kx = min(63u, (unsigned)(xs * 64.0f));
    unsigned ky = min(31u, (unsigned)(ys * 32.0f));
    unsigned kz = min(31u, (unsigned)(zs * 32.0f));
    unsigned key = ((kx >> 5) << 15)
                 | (spread5(kx & 31u) << 2)
                 | (spread5(ky) << 1)
                 | spread5(kz);
    keyA[i] = (unsigned short)key;
    atomicAdd(&planes[(i & (NSHARD - 1)) * NKEYS + key], 1u);
}

__global__ __launch_bounds__(256) void he_scanShards(unsigned* __restrict__ planes,
                                                     unsigned* __restrict__ keytot) {
    int k = blockIdx.x * 256 + threadIdx.x;
    unsigned c[NSHARD];
    #pragma unroll
    for (int s = 0; s < NSHARD; ++s) c[s] = planes[s * NKEYS + k];
    unsigned run = 0;
    #pragma unroll
    for (int s = 0; s < NSHARD; ++s) {
        planes[s * NKEYS + k] = run;
        run += c[s];
    }
    keytot[k] = run;
}

__global__ __launch_bounds__(256) void he_scanA(unsigned* __restrict__ keytot,
                                                unsigned* __restrict__ bsum) {
    __shared__ unsigned s[256];
    int tid = threadIdx.x;
    int g = blockIdx.x * 256 + tid;
    unsigned v = keytot[g];
    s[tid] = v;
    __syncthreads();
    #pragma unroll
    for (int off = 1; off < 256; off <<= 1) {
        unsigned t = (tid >= off) ? s[tid - off] : 0u;
        __syncthreads();
        s[tid] += t;
        __syncthreads();
    }
    keytot[g] = s[tid] - v;
    if (tid == 255) bsum[blockIdx.x] = s[255];
}

__global__ __launch_bounds__(256) void he_scanB(unsigned* __restrict__ bsum) {
    __shared__ unsigned s[256];
    int tid = threadIdx.x;
    unsigned v = bsum[tid];
    s[tid] = v;
    __syncthreads();
    #pragma unroll
    for (int off = 1; off < 256; off <<= 1) {
        unsigned t = (tid >= off) ? s[tid - off] : 0u;
        __syncthreads();
        s[tid] += t;
        __syncthreads();
    }
    bsum[tid] = s[tid] - v;
}

__global__ __launch_bounds__(256) void he_scanC(unsigned* __restrict__ planes,
                                                const unsigned* __restrict__ keytot,
                                                const unsigned* __restrict__ bsum) {
    int g = blockIdx.x * 256 + threadIdx.x;
    unsigned base = keytot[g] + bsum[blockIdx.x];
    #pragma unroll
    for (int s = 0; s < NSHARD; ++s) planes[s * NKEYS + g] += base;
}

// scatter: write scaled coords (+orig index) to sorted slot, and rank (inverse
// permutation) coalesced by original index. sidx no longer needed.
__global__ __launch_bounds__(256) void he_scatter(const unsigned short* __restrict__ keyA,
                                                  const float* __restrict__ x, int n,
                                                  const float* __restrict__ mm,
                                                  unsigned* __restrict__ planes,
                                                  f4* __restrict__ xsorted,
                                                  unsigned* __restrict__ rank) {
    int i = blockIdx.x * 256 + threadIdx.x;
    if (i >= n) return;
    float den0 = (mm[3] - mm[0]) + 1e-8f;
    float den1 = (mm[4] - mm[1]) + 1e-8f;
    float den2 = (mm[5] - mm[2]) + 1e-8f;
    float xs = (x[3 * i + 0] - mm[0]) / den0;
    float ys = (x[3 * i + 1] - mm[1]) / den1;
    float zs = (x[3 * i + 2] - mm[2]) / den2;
    unsigned k = keyA[i];
    unsigned pos = atomicAdd(&planes[(i & (NSHARD - 1)) * NKEYS + k], 1u);
    rank[i] = pos;
    f4 v;
    v.x = xs; v.y = ys; v.z = zs; v.w = __uint_as_float((unsigned)i);
    xsorted[pos] = v;
}

// ---------------- encode core (shared) ---------------------------------------
__device__ __forceinline__ void enc_core(float xs, float ys, float zs,
                                         const float* __restrict__ tables,
                                         const ResArr& res, float o[32]) {
    #pragma unroll
    for (int l = 0; l < 16; ++l) {
        float R = res.r[l];
        float xg = xs * R, yg = ys * R, zg = zs * R;
        float fx = floorf(xg), fy = floorf(yg), fz = floorf(zg);
        float tx = xg - fx, ty = yg - fy, tz = zg - fz;
        unsigned cx = (unsigned)fx, cy = (unsigned)fy, cz = (unsigned)fz;

        unsigned hx0 = cx,      hx1 = cx + 1u;
        unsigned hy0 = cy * P2, hy1 = hy0 + P2;
        unsigned hz0 = cz * P3, hz1 = hz0 + P3;

        const float2* __restrict__ T = (const float2*)tables + (size_t)l * HASH_SIZE;

        float2 f000 = T[(hx0 ^ hy0 ^ hz0) & HASH_MASK];
        float2 f100 = T[(hx1 ^ hy0 ^ hz0) & HASH_MASK];
        float2 f010 = T[(hx0 ^ hy1 ^ hz0) & HASH_MASK];
        float2 f110 = T[(hx1 ^ hy1 ^ hz0) & HASH_MASK];
        float2 f001 = T[(hx0 ^ hy0 ^ hz1) & HASH_MASK];
        float2 f101 = T[(hx1 ^ hy0 ^ hz1) & HASH_MASK];
        float2 f011 = T[(hx0 ^ hy1 ^ hz1) & HASH_MASK];
        float2 f111 = T[(hx1 ^ hy1 ^ hz1) & HASH_MASK];

        float wx0 = 1.0f - tx, wx1 = tx;
        float wy0 = 1.0f - ty, wy1 = ty;
        float wz0 = 1.0f - tz, wz1 = tz;

        float w000 = wx0 * wy0 * wz0;
        float w100 = wx1 * wy0 * wz0;
        float w010 = wx0 * wy1 * wz0;
        float w110 = wx1 * wy1 * wz0;
        float w001 = wx0 * wy0 * wz1;
        float w101 = wx1 * wy0 * wz1;
        float w011 = wx0 * wy1 * wz1;
        float w111 = wx1 * wy1 * wz1;

        float a0 = w000 * f000.x;
        float a1 = w000 * f000.y;
        a0 += w100 * f100.x;  a1 += w100 * f100.y;
        a0 += w010 * f010.x;  a1 += w010 * f010.y;
        a0 += w110 * f110.x;  a1 += w110 * f110.y;
        a0 += w001 * f001.x;  a1 += w001 * f001.y;
        a0 += w101 * f101.x;  a1 += w101 * f101.y;
        a0 += w011 * f011.x;  a1 += w011 * f011.y;
        a0 += w111 * f111.x;  a1 += w111 * f111.y;

        o[2 * l + 0] = a0;
        o[2 * l + 1] = a1;
    }
}

__device__ __forceinline__ int swz_block(int b, int nwg) {
    int q = nwg >> 3, r = nwg & 7;
    int xcd = b & 7, kk = b >> 3;
    return (xcd < r ? xcd * (q + 1) : r * (q + 1) + (xcd - r) * q) + kk;
}

// tier2: sorted input -> sorted output (pure streams + table gathers)
__global__ __launch_bounds__(256) void he_encode_sorted(const f4* __restrict__ xsorted,
                                                        const float* __restrict__ tables,
                                                        float* __restrict__ outS, int n, ResArr res) {
    int sb = swz_block(blockIdx.x, gridDim.x);
    int j = sb * 256 + threadIdx.x;
    if (j >= n) return;
    f4 p = xsorted[j];
    float o[32];
    enc_core(p.x, p.y, p.z, tables, res, o);
    float* op = outS + (size_t)j * 32;
    #pragma unroll
    for (int k = 0; k < 8; ++k) {
        f4 v;
        v.x = o[4 * k + 0]; v.y = o[4 * k + 1]; v.z = o[4 * k + 2]; v.w = o[4 * k + 3];
        __builtin_nontemporal_store(v, (f4*)(op + 4 * k));
    }
}

// permute: out[i] = outS[rank[i]]  (coalesced writes, full-line random reads)
__global__ __launch_bounds__(256) void he_permute(const float* __restrict__ outS,
                                                  const unsigned* __restrict__ rank,
                                                  float* __restrict__ out, int n) {
    int i = blockIdx.x * 256 + threadIdx.x;
    if (i >= n) return;
    const f4* src = (const f4*)(outS + (size_t)rank[i] * 32);
    f4* dst = (f4*)(out + (size_t)i * 32);
    #pragma unroll
    for (int k = 0; k < 8; ++k) {
        f4 v = __builtin_nontemporal_load(src + k);
        __builtin_nontemporal_store(v, dst + k);
    }
}

// tier1: sorted input -> direct scattered output (no outS buffer)
__global__ __launch_bounds__(256) void he_encode_scatter(const f4* __restrict__ xsorted,
                                                         const float* __restrict__ tables,
                                                         float* __restrict__ out, int n, ResArr res) {
    int sb = swz_block(blockIdx.x, gridDim.x);
    int j = sb * 256 + threadIdx.x;
    if (j >= n) return;
    f4 p = xsorted[j];
    int i = (int)__float_as_uint(p.w);
    float o[32];
    enc_core(p.x, p.y, p.z, tables, res, o);
    float* op = out + (size_t)i * 32;
    #pragma unroll
    for (int k = 0; k < 8; ++k) {
        f4 v;
        v.x = o[4 * k + 0]; v.y = o[4 * k + 1]; v.z = o[4 * k + 2]; v.w = o[4 * k + 3];
        __builtin_nontemporal_store(v, (f4*)(op + 4 * k));
    }
}

// tier0: unsorted direct
__global__ __launch_bounds__(256) void he_encode_plain(const float* __restrict__ x,
                                                       const float* __restrict__ tables,
                                                       const float* __restrict__ mm,
                                                       float* __restrict__ out, int n, ResArr res) {
    int i = blockIdx.x * 256 + threadIdx.x;
    if (i >= n) return;
    float den0 = (mm[3] - mm[0]) + 1e-8f;
    float den1 = (mm[4] - mm[1]) + 1e-8f;
    float den2 = (mm[5] - mm[2]) + 1e-8f;
    float xs = (x[3 * i + 0] - mm[0]) / den0;
    float ys = (x[3 * i + 1] - mm[1]) / den1;
    float zs = (x[3 * i + 2] - mm[2]) / den2;
    float o[32];
    enc_core(xs, ys, zs, tables, res, o);
    float* op = out + (size_t)i * 32;
    #pragma unroll
    for (int k = 0; k < 8; ++k) {
        f4 v;
        v.x = o[4 * k + 0]; v.y = o[4 * k + 1]; v.z = o[4 * k + 2]; v.w = o[4 * k + 3];
        __builtin_nontemporal_store(v, (f4*)(op + 4 * k));
    }
}

extern "C" void kernel_launch(void* const* d_in, const int* in_sizes, int n_in,
                              void* d_out, int out_size, void* d_ws, size_t ws_size,
                              hipStream_t stream) {
    const float* x = (const float*)d_in[0];
    const float* tables = (const float*)d_in[1];
    float* out = (float*)d_out;
    int n = in_sizes[0] / 3;

    char* w = (char*)d_ws;
    float*          mm      = (float*)w;                         // 24 B
    float*          part    = (float*)(w + 4096);                // 6 KB
    unsigned*       bsum    = (unsigned*)(w + 16384);            // 1 KB
    unsigned*       keytot  = (unsigned*)(w + 32768);            // 256 KB
    unsigned*       planes  = (unsigned*)(w + 524288);           // 2 MB
    unsigned short* keyA    = (unsigned short*)(w + 0x300000);   // 2 MB
    unsigned*       rank    = (unsigned*)(w + 0x500000);         // 4 MB
    f4*             xsorted = (f4*)(w + 0x900000);               // 16 MB
    float*          outS    = (float*)(w + 0x1900000);           // 128 MB

    const size_t NEED1 = 0x1900000;                        // 25 MB (through xsorted)
    const size_t NEED2 = NEED1 + (size_t)134217728;        // +128 MB outS
    int tier = (ws_size >= NEED2) ? 2 : (ws_size >= NEED1) ? 1 : 0;
    if (n > (1 << 20)) tier = 0;

    ResArr res;
    double growth = exp((log(512.0) - log(16.0)) / 15.0);
    for (int l = 0; l < 16; ++l) {
        res.r[l] = (float)(int)(16.0 * pow(growth, (double)l));
    }

    int blocks = (n + 255) / 256;

    he_minmax1<<<256, 256, 0, stream>>>(x, n, part);
    he_minmax2<<<1, 256, 0, stream>>>(part, mm);

    if (tier >= 1) {
        hipMemsetAsync(planes, 0, (size_t)NSHARD * NKEYS * 4, stream);
        he_keys<<<blocks, 256, 0, stream>>>(x, n, mm, planes, keyA);
        he_scanShards<<<NKEYS / 256, 256, 0, stream>>>(planes, keytot);
        he_scanA<<<NKEYS / 256, 256, 0, stream>>>(keytot, bsum);
        he_scanB<<<1, 256, 0, stream>>>(bsum);
        he_scanC<<<NKEYS / 256, 256, 0, stream>>>(planes, keytot, bsum);
        he_scatter<<<blocks, 256, 0, stream>>>(keyA, x, n, mm, planes, xsorted, rank);
        if (tier == 2) {
            he_encode_sorted<<<blocks, 256, 0, stream>>>(xsorted, tables, outS, n, res);
            he_permute<<<blocks, 256, 0, stream>>>(outS, rank, out, n);
        } else {
            he_encode_scatter<<<blocks, 256, 0, stream>>>(xsorted, tables, out, n, res);
        }
    } else {
        he_encode_plain<<<blocks, 256, 0, stream>>>(x, tables, mm, out, n, res);
    }
}

// Round 7
// 328.057 us; speedup vs baseline: 2.0721x; 2.0721x over previous
//
#include <hip/hip_runtime.h>
#include <cmath>

constexpr unsigned HASH_SIZE = 1u << 19;
constexpr unsigned HASH_MASK = HASH_SIZE - 1u;
constexpr unsigned P2 = 2654435761u;
constexpr unsigned P3 = 805459861u;
constexpr int NKEYS = 65536;
constexpr int NSHARD = 8;

struct ResArr { float r[16]; };
typedef float f4 __attribute__((ext_vector_type(4)));

// ---------------- stage 1: per-block min/max partials (no atomics) ----------
__global__ __launch_bounds__(256) void he_minmax1(const float* __restrict__ x, int n,
                                                  float* __restrict__ part) {
    int tid = blockIdx.x * blockDim.x + threadIdx.x;
    int stride = gridDim.x * blockDim.x;
    float mn0 = INFINITY, mn1 = INFINITY, mn2 = INFINITY;
    float mx0 = -INFINITY, mx1 = -INFINITY, mx2 = -INFINITY;
    for (int i = tid; i < n; i += stride) {
        float a = x[3 * i + 0];
        float b = x[3 * i + 1];
        float c = x[3 * i + 2];
        mn0 = fminf(mn0, a); mx0 = fmaxf(mx0, a);
        mn1 = fminf(mn1, b); mx1 = fmaxf(mx1, b);
        mn2 = fminf(mn2, c); mx2 = fmaxf(mx2, c);
    }
    #pragma unroll
    for (int off = 32; off > 0; off >>= 1) {
        mn0 = fminf(mn0, __shfl_down(mn0, off));
        mn1 = fminf(mn1, __shfl_down(mn1, off));
        mn2 = fminf(mn2, __shfl_down(mn2, off));
        mx0 = fmaxf(mx0, __shfl_down(mx0, off));
        mx1 = fmaxf(mx1, __shfl_down(mx1, off));
        mx2 = fmaxf(mx2, __shfl_down(mx2, off));
    }
    __shared__ float s[6][4];
    int w = threadIdx.x >> 6;
    if ((threadIdx.x & 63) == 0) {
        s[0][w] = mn0; s[1][w] = mn1; s[2][w] = mn2;
        s[3][w] = mx0; s[4][w] = mx1; s[5][w] = mx2;
    }
    __syncthreads();
    if (threadIdx.x == 0) {
        float* p = part + 6 * blockIdx.x;
        p[0] = fminf(fminf(s[0][0], s[0][1]), fminf(s[0][2], s[0][3]));
        p[1] = fminf(fminf(s[1][0], s[1][1]), fminf(s[1][2], s[1][3]));
        p[2] = fminf(fminf(s[2][0], s[2][1]), fminf(s[2][2], s[2][3]));
        p[3] = fmaxf(fmaxf(s[3][0], s[3][1]), fmaxf(s[3][2], s[3][3]));
        p[4] = fmaxf(fmaxf(s[4][0], s[4][1]), fmaxf(s[4][2], s[4][3]));
        p[5] = fmaxf(fmaxf(s[5][0], s[5][1]), fmaxf(s[5][2], s[5][3]));
    }
}

// ---------------- stage 2: combine 256 partials ----------------------------
__global__ __launch_bounds__(256) void he_minmax2(const float* __restrict__ part,
                                                  float* __restrict__ mm) {
    int t = threadIdx.x;
    const float* p = part + 6 * t;
    float mn0 = p[0], mn1 = p[1], mn2 = p[2];
    float mx0 = p[3], mx1 = p[4], mx2 = p[5];
    #pragma unroll
    for (int off = 32; off > 0; off >>= 1) {
        mn0 = fminf(mn0, __shfl_down(mn0, off));
        mn1 = fminf(mn1, __shfl_down(mn1, off));
        mn2 = fminf(mn2, __shfl_down(mn2, off));
        mx0 = fmaxf(mx0, __shfl_down(mx0, off));
        mx1 = fmaxf(mx1, __shfl_down(mx1, off));
        mx2 = fmaxf(mx2, __shfl_down(mx2, off));
    }
    __shared__ float s[6][4];
    int w = t >> 6;
    if ((t & 63) == 0) {
        s[0][w] = mn0; s[1][w] = mn1; s[2][w] = mn2;
        s[3][w] = mx0; s[4][w] = mx1; s[5][w] = mx2;
    }
    __syncthreads();
    if (t == 0) {
        mm[0] = fminf(fminf(s[0][0], s[0][1]), fminf(s[0][2], s[0][3]));
        mm[1] = fminf(fminf(s[1][0], s[1][1]), fminf(s[1][2], s[1][3]));
        mm[2] = fminf(fminf(s[2][0], s[2][1]), fminf(s[2][2], s[2][3]));
        mm[3] = fmaxf(fmaxf(s[3][0], s[3][1]), fmaxf(s[3][2], s[3][3]));
        mm[4] = fmaxf(fmaxf(s[4][0], s[4][1]), fmaxf(s[4][2], s[4][3]));
        mm[5] = fmaxf(fmaxf(s[5][0], s[5][1]), fmaxf(s[5][2], s[5][3]));
    }
}

// ---------------- sort passes ------------------------------------------------
__device__ __forceinline__ unsigned spread5(unsigned v) {
    return (v & 1u) | ((v & 2u) << 2) | ((v & 4u) << 4) | ((v & 8u) << 6) | ((v & 16u) << 8);
}

__global__ __launch_bounds__(256) void he_keys(const float* __restrict__ x, int n,
                                               const float* __restrict__ mm,
                                               unsigned* __restrict__ planes,
                                               unsigned short* __restrict__ keyA) {
    int i = blockIdx.x * 256 + threadIdx.x;
    if (i >= n) return;
    float den0 = (mm[3] - mm[0]) + 1e-8f;
    float den1 = (mm[4] - mm[1]) + 1e-8f;
    float den2 = (mm[5] - mm[2]) + 1e-8f;
    float xs = (x[3 * i + 0] - mm[0]) / den0;
    float ys = (x[3 * i + 1] - mm[1]) / den1;
    float zs = (x[3 * i + 2] - mm[2]) / den2;
    unsigned kx = min(63u, (unsigned)(xs * 64.0f));
    unsigned ky = min(31u, (unsigned)(ys * 32.0f));
    unsigned kz = min(31u, (unsigned)(zs * 32.0f));
    unsigned key = ((kx >> 5) << 15)
                 | (spread5(kx & 31u) << 2)
                 | (spread5(ky) << 1)
                 | spread5(kz);
    keyA[i] = (unsigned short)key;
    atomicAdd(&planes[(i & (NSHARD - 1)) * NKEYS + key], 1u);
}

__global__ __launch_bounds__(256) void he_scanShards(unsigned* __restrict__ planes,
                                                     unsigned* __restrict__ keytot) {
    int k = blockIdx.x * 256 + threadIdx.x;
    unsigned c[NSHARD];
    #pragma unroll
    for (int s = 0; s < NSHARD; ++s) c[s] = planes[s * NKEYS + k];
    unsigned run = 0;
    #pragma unroll
    for (int s = 0; s < NSHARD; ++s) {
        planes[s * NKEYS + k] = run;
        run += c[s];
    }
    keytot[k] = run;
}

__global__ __launch_bounds__(256) void he_scanA(unsigned* __restrict__ keytot,
                                                unsigned* __restrict__ bsum) {
    __shared__ unsigned s[256];
    int tid = threadIdx.x;
    int g = blockIdx.x * 256 + tid;
    unsigned v = keytot[g];
    s[tid] = v;
    __syncthreads();
    #pragma unroll
    for (int off = 1; off < 256; off <<= 1) {
        unsigned t = (tid >= off) ? s[tid - off] : 0u;
        __syncthreads();
        s[tid] += t;
        __syncthreads();
    }
    keytot[g] = s[tid] - v;
    if (tid == 255) bsum[blockIdx.x] = s[255];
}

__global__ __launch_bounds__(256) void he_scanB(unsigned* __restrict__ bsum) {
    __shared__ unsigned s[256];
    int tid = threadIdx.x;
    unsigned v = bsum[tid];
    s[tid] = v;
    __syncthreads();
    #pragma unroll
    for (int off = 1; off < 256; off <<= 1) {
        unsigned t = (tid >= off) ? s[tid - off] : 0u;
        __syncthreads();
        s[tid] += t;
        __syncthreads();
    }
    bsum[tid] = s[tid] - v;
}

__global__ __launch_bounds__(256) void he_scanC(unsigned* __restrict__ planes,
                                                const unsigned* __restrict__ keytot,
                                                const unsigned* __restrict__ bsum) {
    int g = blockIdx.x * 256 + threadIdx.x;
    unsigned base = keytot[g] + bsum[blockIdx.x];
    #pragma unroll
    for (int s = 0; s < NSHARD; ++s) planes[s * NKEYS + g] += base;
}

// scatter scaled coords (+orig index) to sorted slot (rank no longer needed)
__global__ __launch_bounds__(256) void he_scatter(const unsigned short* __restrict__ keyA,
                                                  const float* __restrict__ x, int n,
                                                  const float* __restrict__ mm,
                                                  unsigned* __restrict__ planes,
                                                  f4* __restrict__ xsorted) {
    int i = blockIdx.x * 256 + threadIdx.x;
    if (i >= n) return;
    float den0 = (mm[3] - mm[0]) + 1e-8f;
    float den1 = (mm[4] - mm[1]) + 1e-8f;
    float den2 = (mm[5] - mm[2]) + 1e-8f;
    float xs = (x[3 * i + 0] - mm[0]) / den0;
    float ys = (x[3 * i + 1] - mm[1]) / den1;
    float zs = (x[3 * i + 2] - mm[2]) / den2;
    unsigned k = keyA[i];
    unsigned pos = atomicAdd(&planes[(i & (NSHARD - 1)) * NKEYS + k], 1u);
    f4 v;
    v.x = xs; v.y = ys; v.z = zs; v.w = __uint_as_float((unsigned)i);
    xsorted[pos] = v;
}

// ---------------- encode core (shared) ---------------------------------------
__device__ __forceinline__ void enc_core(float xs, float ys, float zs,
                                         const float* __restrict__ tables,
                                         const ResArr& res, float o[32]) {
    #pragma unroll
    for (int l = 0; l < 16; ++l) {
        float R = res.r[l];
        float xg = xs * R, yg = ys * R, zg = zs * R;
        float fx = floorf(xg), fy = floorf(yg), fz = floorf(zg);
        float tx = xg - fx, ty = yg - fy, tz = zg - fz;
        unsigned cx = (unsigned)fx, cy = (unsigned)fy, cz = (unsigned)fz;

        unsigned hx0 = cx,      hx1 = cx + 1u;
        unsigned hy0 = cy * P2, hy1 = hy0 + P2;
        unsigned hz0 = cz * P3, hz1 = hz0 + P3;

        const float2* __restrict__ T = (const float2*)tables + (size_t)l * HASH_SIZE;

        float2 f000 = T[(hx0 ^ hy0 ^ hz0) & HASH_MASK];
        float2 f100 = T[(hx1 ^ hy0 ^ hz0) & HASH_MASK];
        float2 f010 = T[(hx0 ^ hy1 ^ hz0) & HASH_MASK];
        float2 f110 = T[(hx1 ^ hy1 ^ hz0) & HASH_MASK];
        float2 f001 = T[(hx0 ^ hy0 ^ hz1) & HASH_MASK];
        float2 f101 = T[(hx1 ^ hy0 ^ hz1) & HASH_MASK];
        float2 f011 = T[(hx0 ^ hy1 ^ hz1) & HASH_MASK];
        float2 f111 = T[(hx1 ^ hy1 ^ hz1) & HASH_MASK];

        float wx0 = 1.0f - tx, wx1 = tx;
        float wy0 = 1.0f - ty, wy1 = ty;
        float wz0 = 1.0f - tz, wz1 = tz;

        float w000 = wx0 * wy0 * wz0;
        float w100 = wx1 * wy0 * wz0;
        float w010 = wx0 * wy1 * wz0;
        float w110 = wx1 * wy1 * wz0;
        float w001 = wx0 * wy0 * wz1;
        float w101 = wx1 * wy0 * wz1;
        float w011 = wx0 * wy1 * wz1;
        float w111 = wx1 * wy1 * wz1;

        float a0 = w000 * f000.x;
        float a1 = w000 * f000.y;
        a0 += w100 * f100.x;  a1 += w100 * f100.y;
        a0 += w010 * f010.x;  a1 += w010 * f010.y;
        a0 += w110 * f110.x;  a1 += w110 * f110.y;
        a0 += w001 * f001.x;  a1 += w001 * f001.y;
        a0 += w101 * f101.x;  a1 += w101 * f101.y;
        a0 += w011 * f011.x;  a1 += w011 * f011.y;
        a0 += w111 * f111.x;  a1 += w111 * f111.y;

        o[2 * l + 0] = a0;
        o[2 * l + 1] = a1;
    }
}

__device__ __forceinline__ int swz_block(int b, int nwg) {
    int q = nwg >> 3, r = nwg & 7;
    int xcd = b & 7, kk = b >> 3;
    return (xcd < r ? xcd * (q + 1) : r * (q + 1) + (xcd - r) * q) + kk;
}

// sorted input -> direct scattered output, PLAIN stores (each point fully
// writes one aligned 128B line; r5/r6 showed 16B nt stores amplify ~3-4x on
// the write side, so trade nt's no-pollution for plain's exact-bytes)
__global__ __launch_bounds__(256) void he_encode_scatter(const f4* __restrict__ xsorted,
                                                         const float* __restrict__ tables,
                                                         float* __restrict__ out, int n, ResArr res) {
    int sb = swz_block(blockIdx.x, gridDim.x);
    int j = sb * 256 + threadIdx.x;
    if (j >= n) return;
    f4 p = xsorted[j];
    int i = (int)__float_as_uint(p.w);
    float o[32];
    enc_core(p.x, p.y, p.z, tables, res, o);
    float* op = out + (size_t)i * 32;
    #pragma unroll
    for (int k = 0; k < 8; ++k) {
        f4 v;
        v.x = o[4 * k + 0]; v.y = o[4 * k + 1]; v.z = o[4 * k + 2]; v.w = o[4 * k + 3];
        *(f4*)(op + 4 * k) = v;
    }
}

// tier0: unsorted direct
__global__ __launch_bounds__(256) void he_encode_plain(const float* __restrict__ x,
                                                       const float* __restrict__ tables,
                                                       const float* __restrict__ mm,
                                                       float* __restrict__ out, int n, ResArr res) {
    int i = blockIdx.x * 256 + threadIdx.x;
    if (i >= n) return;
    float den0 = (mm[3] - mm[0]) + 1e-8f;
    float den1 = (mm[4] - mm[1]) + 1e-8f;
    float den2 = (mm[5] - mm[2]) + 1e-8f;
    float xs = (x[3 * i + 0] - mm[0]) / den0;
    float ys = (x[3 * i + 1] - mm[1]) / den1;
    float zs = (x[3 * i + 2] - mm[2]) / den2;
    float o[32];
    enc_core(xs, ys, zs, tables, res, o);
    float* op = out + (size_t)i * 32;
    #pragma unroll
    for (int k = 0; k < 8; ++k) {
        f4 v;
        v.x = o[4 * k + 0]; v.y = o[4 * k + 1]; v.z = o[4 * k + 2]; v.w = o[4 * k + 3];
        __builtin_nontemporal_store(v, (f4*)(op + 4 * k));
    }
}

extern "C" void kernel_launch(void* const* d_in, const int* in_sizes, int n_in,
                              void* d_out, int out_size, void* d_ws, size_t ws_size,
                              hipStream_t stream) {
    const float* x = (const float*)d_in[0];
    const float* tables = (const float*)d_in[1];
    float* out = (float*)d_out;
    int n = in_sizes[0] / 3;

    char* w = (char*)d_ws;
    float*          mm      = (float*)w;                         // 24 B
    float*          part    = (float*)(w + 4096);                // 6 KB
    unsigned*       bsum    = (unsigned*)(w + 16384);            // 1 KB
    unsigned*       keytot  = (unsigned*)(w + 32768);            // 256 KB
    unsigned*       planes  = (unsigned*)(w + 524288);           // 2 MB
    unsigned short* keyA    = (unsigned short*)(w + 0x300000);   // 2 MB
    f4*             xsorted = (f4*)(w + 0x500000);               // 16 MB

    const size_t NEED1 = 0x500000 + (size_t)16777216;            // 21 MB
    int tier = (ws_size >= NEED1) ? 1 : 0;
    if (n > (1 << 20)) tier = 0;

    ResArr res;
    double growth = exp((log(512.0) - log(16.0)) / 15.0);
    for (int l = 0; l < 16; ++l) {
        res.r[l] = (float)(int)(16.0 * pow(growth, (double)l));
    }

    int blocks = (n + 255) / 256;

    he_minmax1<<<256, 256, 0, stream>>>(x, n, part);
    he_minmax2<<<1, 256, 0, stream>>>(part, mm);

    if (tier >= 1) {
        hipMemsetAsync(planes, 0, (size_t)NSHARD * NKEYS * 4, stream);
        he_keys<<<blocks, 256, 0, stream>>>(x, n, mm, planes, keyA);
        he_scanShards<<<NKEYS / 256, 256, 0, stream>>>(planes, keytot);
        he_scanA<<<NKEYS / 256, 256, 0, stream>>>(keytot, bsum);
        he_scanB<<<1, 256, 0, stream>>>(bsum);
        he_scanC<<<NKEYS / 256, 256, 0, stream>>>(planes, keytot, bsum);
        he_scatter<<<blocks, 256, 0, stream>>>(keyA, x, n, mm, planes, xsorted);
        he_encode_scatter<<<blocks, 256, 0, stream>>>(xsorted, tables, out, n, res);
    } else {
        he_encode_plain<<<blocks, 256, 0, stream>>>(x, tables, mm, out, n, res);
    }
}